// Round 3
// baseline (1291.123 us; speedup 1.0000x reference)
//
#include <hip/hip_runtime.h>
#include <hip/hip_bf16.h>

#define N_  50000
#define R_  1000
#define A_  5000
#define D_  256
#define H_  4
#define DH_ 64
#define E_  200000
#define ER_ 150000
#define EA_ 150000

// ---------- monotone float<->uint key for atomicMax on floats ----------
__device__ __forceinline__ unsigned f2key(float f) {
    unsigned b = __float_as_uint(f);
    return (b & 0x80000000u) ? ~b : (b | 0x80000000u);
}
__device__ __forceinline__ float key2f(unsigned k) {
    unsigned b = (k & 0x80000000u) ? (k ^ 0x80000000u) : ~k;
    return __uint_as_float(b);
}

// ---------- concept: atomic mean-aggregate ----------
__global__ void k_concept_accum(const int* __restrict__ idx, const float* __restrict__ emb,
                                float* __restrict__ sum, int* __restrict__ deg, int nE) {
    int gid = blockIdx.x * blockDim.x + threadIdx.x;
    if (gid >= nE * 64) return;
    int e = gid >> 6, d = gid & 63;
    int row = idx[2 * e], col = idx[2 * e + 1];
    atomicAdd(&sum[row * 64 + d], emb[col * 64 + d]);
    if (d == 0) atomicAdd(&deg[row], 1);
}

__global__ void k_concept_final(const float* __restrict__ sum_rel, const int* __restrict__ deg_rel,
                                const float* __restrict__ sum_attr, const int* __restrict__ deg_attr,
                                float* __restrict__ out) {
    int gid = blockIdx.x * blockDim.x + threadIdx.x;
    if (gid >= N_ * 128) return;
    int n = gid >> 7, d = gid & 127;
    float v;
    if (d < 64) {
        int dg = deg_rel[n];
        v = dg > 0 ? sum_rel[n * 64 + d] / (float)dg : 0.f;
    } else {
        int dg = deg_attr[n];
        v = dg > 0 ? sum_attr[n * 64 + (d - 64)] / (float)dg : 0.f;
    }
    v = fmaxf(v, 0.f);
    out[(size_t)n * 640 + 512 + d] = v;                      // ent_out cols 512..639
    out[(size_t)N_ * 640 + (size_t)n * 128 + d] = v;         // conc
}

// ---------- h0 stage: per-row softmax(edge_val) weighted sum of ent_emb[col] ----------
__global__ void k_h0_denom(const int* __restrict__ eidx, const float* __restrict__ eval,
                           float* __restrict__ z0) {
    int e = blockIdx.x * blockDim.x + threadIdx.x;
    if (e >= E_) return;
    atomicAdd(&z0[eidx[2 * e]], expf(eval[e]));
}

__global__ void k_h0_scatter(const int* __restrict__ eidx, const float* __restrict__ eval,
                             const float* __restrict__ z0, const float* __restrict__ ent_emb,
                             float* __restrict__ h0) {
    long long gid = (long long)blockIdx.x * blockDim.x + threadIdx.x;
    if (gid >= (long long)E_ * 256) return;
    int e = (int)(gid >> 8), d = (int)(gid & 255);
    int row = eidx[2 * e], col = eidx[2 * e + 1];
    float w = expf(eval[e]) / z0[row];
    atomicAdd(&h0[(size_t)row * 256 + d], w * ent_emb[(size_t)col * 256 + d]);
}

// ---------- per-node transform: s1/s2 attention halves ----------
__global__ void k_transform(const float* __restrict__ h, const float* __restrict__ Wk,
                            const float* __restrict__ ak, float* __restrict__ s1,
                            float* __restrict__ s2) {
    int n = blockIdx.x;
    int lane = threadIdx.x & 63;
    int head = threadIdx.x >> 6;             // 4 heads = 4 waves/block
    const float* W = Wk + head * 64 * 64;    // (d,f) row-major
    const float* hr = h + (size_t)n * 256 + head * 64;
    float t = 0.f;
    for (int d = 0; d < 64; ++d) {
        float hv = fmaxf(hr[d], 0.f);        // relu(h)
        t += hv * W[d * 64 + lane];
    }
    t = fmaxf(t, 0.f);                       // relu(W h)
    float p1 = t * ak[head * 128 + lane];        // self (row) side: ak[:, :64]
    float p2 = t * ak[head * 128 + 64 + lane];   // neighbor (col) side: ak[:, 64:]
    for (int s = 32; s >= 1; s >>= 1) {
        p1 += __shfl_xor(p1, s, 64);
        p2 += __shfl_xor(p2, s, 64);
    }
    if (lane == 0) { s1[n * 4 + head] = p1; s2[n * 4 + head] = p2; }
}

// ---------- attention pass 1: score + leaky-relu + global max per head ----------
__global__ void k_attn1(const int* __restrict__ eidx,
                        const float* __restrict__ s1, const float* __restrict__ s2,
                        float* __restrict__ a_arr, unsigned* __restrict__ Mkey) {
    __shared__ unsigned smax[4];
    int tid = threadIdx.x;
    if (tid < 4) smax[tid] = 0u;
    __syncthreads();
    long long gid = (long long)blockIdx.x * blockDim.x + tid;
    if (gid < (long long)E_ * 4) {
        int e = (int)(gid >> 2), hh = (int)(gid & 3);
        float a = s1[eidx[2 * e] * 4 + hh] + s2[eidx[2 * e + 1] * 4 + hh];
        a = (a > 0.f) ? a : 0.3f * a;        // leaky_relu(0.3)
        a_arr[gid] = a;
        atomicMax(&smax[hh], f2key(a));
    }
    __syncthreads();
    if (tid < 4 && smax[tid]) atomicMax(&Mkey[tid], smax[tid]);
}

// ---------- attention pass 2: sum of exp (global softmax denom) ----------
__global__ void k_attn2(float* __restrict__ a_arr, const unsigned* __restrict__ Mkey,
                        float* __restrict__ S) {
    __shared__ float ssum[4];
    int tid = threadIdx.x;
    if (tid < 4) ssum[tid] = 0.f;
    __syncthreads();
    long long gid = (long long)blockIdx.x * blockDim.x + tid;
    if (gid < (long long)E_ * 4) {
        int hh = (int)(gid & 3);
        float v = expf(a_arr[gid] - key2f(Mkey[hh]));
        a_arr[gid] = v;
        atomicAdd(&ssum[hh], v);
    }
    __syncthreads();
    if (tid < 4 && ssum[tid] != 0.f) atomicAdd(&S[tid], ssum[tid]);
}

// ---------- attention pass 3: normalize -> exp for segment softmax -> row sums ----------
__global__ void k_attn3(const int* __restrict__ eidx, float* __restrict__ a_arr,
                        const float* __restrict__ S, float* __restrict__ zl) {
    long long gid = (long long)blockIdx.x * blockDim.x + threadIdx.x;
    if (gid >= (long long)E_ * 4) return;
    int e = (int)(gid >> 2), hh = (int)(gid & 3);
    float v = a_arr[gid] / S[hh];            // global softmax value in [0,1]
    float ev = expf(v);                      // seg-softmax numerator (shift-invariant)
    a_arr[gid] = ev;
    atomicAdd(&zl[eidx[2 * e] * 4 + hh], ev);
}

// ---------- aggregation scatter: acc[row] += w_eh * relu(h_in[col]) ----------
__global__ void k_aggr_scatter(const int* __restrict__ eidx, const float* __restrict__ a_arr,
                               const float* __restrict__ zl, const float* __restrict__ h_in,
                               float* __restrict__ acc) {
    long long gid = (long long)blockIdx.x * blockDim.x + threadIdx.x;
    if (gid >= (long long)E_ * 256) return;
    int e = (int)(gid >> 8), d = (int)(gid & 255);
    int head = d >> 6;
    int row = eidx[2 * e], col = eidx[2 * e + 1];
    float w = a_arr[e * 4 + head] / zl[row * 4 + head];
    float hv = fmaxf(h_in[(size_t)col * 256 + d], 0.f);
    atomicAdd(&acc[(size_t)row * 256 + d], w * hv);
}

// ---------- finalize: tanh, write out (f32) and next-layer h (in place) ----------
__global__ void k_finalize(float* __restrict__ acc, float* __restrict__ out, int layer) {
    int gid = blockIdx.x * blockDim.x + threadIdx.x;
    if (gid >= N_ * 256) return;
    int n = gid >> 8, d = gid & 255;
    float o = tanhf(acc[gid]);
    acc[gid] = o;                                        // h for next layer
    out[(size_t)n * 640 + layer * 256 + d] = o;
}

// ---------- host ----------
static inline size_t align256(size_t x) { return (x + 255) & ~(size_t)255; }

extern "C" void kernel_launch(void* const* d_in, const int* in_sizes, int n_in,
                              void* d_out, int out_size, void* d_ws, size_t ws_size,
                              hipStream_t stream) {
    const float* ent_emb     = (const float*)d_in[0];
    const float* rel_emb     = (const float*)d_in[1];
    const float* attr_emb    = (const float*)d_in[2];
    const float* ent_kernels = (const float*)d_in[3];  // (L,H,64,64)
    const float* ent_attn    = (const float*)d_in[4];  // (L,H,128)
    const float* edge_val    = (const float*)d_in[5];
    const int*   edge_index  = (const int*)d_in[6];
    const int*   rel_index   = (const int*)d_in[7];
    const int*   attr_index  = (const int*)d_in[8];
    float* out = (float*)d_out;   // reference output dtype is float32

    char* w = (char*)d_ws;
    size_t off = 0;
    auto carve = [&](size_t bytes) { void* p = w + off; off += align256(bytes); return p; };

    // group A (zeroed once): concept sums/degrees + h0 softmax denom
    size_t gA_beg = off;
    float* sum_rel  = (float*)carve((size_t)N_ * 64 * 4);
    float* sum_attr = (float*)carve((size_t)N_ * 64 * 4);
    int*   deg_rel  = (int*)carve((size_t)N_ * 4);
    int*   deg_attr = (int*)carve((size_t)N_ * 4);
    float* z0       = (float*)carve((size_t)N_ * 4);
    size_t gA_size = off - gA_beg;

    float* s1    = (float*)carve((size_t)N_ * 4 * 4);
    float* s2    = (float*)carve((size_t)N_ * 4 * 4);
    float* a_arr = (float*)carve((size_t)E_ * 4 * 4);

    // group B (zeroed per layer): seg-softmax row sums + global max/denom
    size_t gB_beg = off;
    float*    zl   = (float*)carve((size_t)N_ * 4 * 4);
    unsigned* Mkey = (unsigned*)carve(4 * 4);
    float*    S    = (float*)carve(4 * 4);
    size_t gB_size = off - gB_beg;

    float* h_a = (float*)carve((size_t)N_ * 256 * 4);
    float* h_b = (float*)carve((size_t)N_ * 256 * 4);

    // ---- concept aggregations ----
    hipMemsetAsync(w + gA_beg, 0, gA_size, stream);
    k_concept_accum<<<(ER_ * 64 + 255) / 256, 256, 0, stream>>>(rel_index, rel_emb, sum_rel, deg_rel, ER_);
    k_concept_accum<<<(EA_ * 64 + 255) / 256, 256, 0, stream>>>(attr_index, attr_emb, sum_attr, deg_attr, EA_);
    k_concept_final<<<(N_ * 128 + 255) / 256, 256, 0, stream>>>(sum_rel, deg_rel, sum_attr, deg_attr, out);

    // ---- h0: edge-softmax weighted aggregation of ent_emb ----
    k_h0_denom<<<(E_ + 255) / 256, 256, 0, stream>>>(edge_index, edge_val, z0);
    hipMemsetAsync(h_a, 0, (size_t)N_ * 256 * 4, stream);
    {
        long long tot = (long long)E_ * 256;
        k_h0_scatter<<<(unsigned)((tot + 255) / 256), 256, 0, stream>>>(edge_index, edge_val, z0, ent_emb, h_a);
    }

    // ---- 2 GAT layers ----
    for (int l = 0; l < 2; ++l) {
        float* h_in = (l == 0) ? h_a : h_b;
        float* acc  = (l == 0) ? h_b : h_a;
        k_transform<<<N_, 256, 0, stream>>>(h_in, ent_kernels + (size_t)l * H_ * 64 * 64,
                                            ent_attn + (size_t)l * H_ * 128, s1, s2);
        hipMemsetAsync(w + gB_beg, 0, gB_size, stream);
        hipMemsetAsync(acc, 0, (size_t)N_ * 256 * 4, stream);
        k_attn1<<<(E_ * 4 + 255) / 256, 256, 0, stream>>>(edge_index, s1, s2, a_arr, Mkey);
        k_attn2<<<(E_ * 4 + 255) / 256, 256, 0, stream>>>(a_arr, Mkey, S);
        k_attn3<<<(E_ * 4 + 255) / 256, 256, 0, stream>>>(edge_index, a_arr, S, zl);
        {
            long long tot = (long long)E_ * 256;
            k_aggr_scatter<<<(unsigned)((tot + 255) / 256), 256, 0, stream>>>(edge_index, a_arr, zl, h_in, acc);
        }
        k_finalize<<<(N_ * 256 + 255) / 256, 256, 0, stream>>>(acc, out, l);
    }
}